// Round 3
// baseline (404.291 us; speedup 1.0000x reference)
//
#include <hip/hip_runtime.h>

#define DIMK 33
#define D2   (DIMK * DIMK)        // 1089
#define D3   (DIMK * DIMK * DIMK) // 35937 vertices
#define HWPIX (2048 * 2048)       // 4194304 = 2^22
#define HWSHIFT 22
#define IMG3  (3 * HWPIX)         // plane stride per image

typedef float        f32x4 __attribute__((ext_vector_type(4)));
typedef float        f32x2 __attribute__((ext_vector_type(2)));
typedef unsigned int u32;

// ---------------------------------------------------------------------------
// Shared prologue: block-private absmax (exact -> identical in every block)
// + quantize whole LUT into LDS as 3x10-bit biased fields per vertex.
// ---------------------------------------------------------------------------
__device__ __forceinline__ void lut_prologue(const float* __restrict__ LUT,
                                             u32* tab, float* red, int tid,
                                             float& s511, float& bias) {
    float m = 0.0f;
    {
        const int n4 = (3 * D3) >> 2;             // 26952 f32x4 groups
        const f32x4* L4 = (const f32x4*)LUT;
        for (int i = tid; i < n4; i += 1024) {
            f32x4 v = L4[i];
            m = fmaxf(m, fmaxf(fmaxf(fabsf(v.x), fabsf(v.y)),
                               fmaxf(fabsf(v.z), fabsf(v.w))));
        }
        for (int i = (n4 << 2) + tid; i < 3 * D3; i += 1024)  // 3-elem tail
            m = fmaxf(m, fabsf(LUT[i]));
    }
    for (int off = 32; off; off >>= 1)
        m = fmaxf(m, __shfl_down(m, off, 64));
    if ((tid & 63) == 0) red[tid >> 6] = m;
    __syncthreads();
    if (tid == 0) {
        float mm = red[0];
#pragma unroll
        for (int i = 1; i < 16; ++i) mm = fmaxf(mm, red[i]);
        red[0] = fmaxf(mm, 1e-20f);
    }
    __syncthreads();
    const float s   = red[0];
    const float inv = 511.0f / s;
    s511 = s * (1.0f / 511.0f);
    bias = 512.0f * s511;
    // word = (q0+512) | (q1+512)<<10 | (q2+512)<<20, q = round(v/s * 511)
    for (int v = tid; v < D3; v += 1024) {
        u32 w = 0;
#pragma unroll
        for (int c = 0; c < 3; ++c) {
            float vv = LUT[c * D3 + v];
            int q = (int)rintf(vv * inv);
            q = max(-511, min(511, q));
            w |= ((u32)(q + 512)) << (10 * c);
        }
        tab[v] = w;
    }
    __syncthreads();
}

// ---------------------------------------------------------------------------
// Interpolate one quad (4 pixels). (A0,A1) accumulate as float2 so the
// backend can form v_pk_fma_f32 (gfx90a+ packed fp32); identical math if not.
// ch2 extract is a bare >>20 (bits 30-31 are zero by construction).
// ---------------------------------------------------------------------------
__device__ __forceinline__ void apply_quad(const u32* __restrict__ tab,
                                           const f32x4& r4, const f32x4& g4,
                                           const f32x4& b4, float s511, float bias,
                                           f32x4& oc0, f32x4& oc1, f32x4& oc2) {
    int   vid[4];
    float fr[4], fg[4], fb[4];
#pragma unroll
    for (int i = 0; i < 4; ++i) {
        float cr = r4[i] * 32.0f;
        float cg = g4[i] * 32.0f;
        float cb = b4[i] * 32.0f;
        int ri = max(0, min(31, (int)cr));
        int gi = max(0, min(31, (int)cg));
        int bi = max(0, min(31, (int)cb));
        fr[i] = cr - (float)ri;
        fg[i] = cg - (float)gi;
        fb[i] = cb - (float)bi;
        vid[i] = bi * D2 + gi * DIMK + ri;
    }

    u32 cw[4][8];
#pragma unroll
    for (int i = 0; i < 4; ++i) {
        int v = vid[i];
        cw[i][0] = tab[v];
        cw[i][1] = tab[v + 1];
        cw[i][2] = tab[v + DIMK];
        cw[i][3] = tab[v + DIMK + 1];
        cw[i][4] = tab[v + D2];
        cw[i][5] = tab[v + D2 + 1];
        cw[i][6] = tab[v + D2 + DIMK];
        cw[i][7] = tab[v + D2 + DIMK + 1];
    }

#pragma unroll
    for (int i = 0; i < 4; ++i) {
        float wr0 = 1.0f - fr[i], wg0 = 1.0f - fg[i], wb0 = 1.0f - fb[i];
        float wbg00 = wb0 * wg0,   wbg01 = wb0 * fg[i];
        float wbg10 = fb[i] * wg0, wbg11 = fb[i] * fg[i];
        float w[8] = {wbg00 * wr0, wbg00 * fr[i], wbg01 * wr0, wbg01 * fr[i],
                      wbg10 * wr0, wbg10 * fr[i], wbg11 * wr0, wbg11 * fr[i]};
        f32x2 a01 = {0.f, 0.f};
        float a2 = 0.f;
#pragma unroll
        for (int cn = 0; cn < 8; ++cn) {
            u32 c = cw[i][cn];
            f32x2 f01 = {(float)(c & 1023u), (float)((c >> 10) & 1023u)};
            f32x2 w2  = {w[cn], w[cn]};
            a01 += w2 * f01;
            a2  += w[cn] * (float)(c >> 20);   // bits 30-31 are zero
        }
        oc0[i] = a01.x * s511 - bias;
        oc1[i] = a01.y * s511 - bias;
        oc2[i] = a2    * s511 - bias;
    }
}

// ---------------------------------------------------------------------------
// Fast path: npix == 4*HWPIX exactly, grid fixed at 256x1024.
// stride*4 = 2^20 divides HWPIX -> every thread runs exactly 16 iterations:
//   addr(i) = (i>>2)*IMG3 + ((i&3)<<20) + p0, channels at +HWPIX steps.
// No bounds checks anywhere; prefetch is unconditional (min(i+2,15) re-loads
// iter-15 data, which is L2-resident). 2-deep pipeline as before.
// ---------------------------------------------------------------------------
__global__ __launch_bounds__(1024, 4) void k_lut_fast(const float* __restrict__ x,
                                                      const float* __restrict__ LUT,
                                                      float* __restrict__ out) {
    __shared__ u32   tab[D3];
    __shared__ float red[16];

    const int tid = threadIdx.x;
    const int p0  = (blockIdx.x * 1024 + tid) << 2;   // [0, 2^20)

    // ---- issue iter-0 and iter-1 loads before the prologue ----
    f32x4 r4, g4, b4, nr, ng, nb;
    {
        const float* xb0 = x + p0;                    // d(0) = 0
        r4 = __builtin_nontemporal_load((const f32x4*)(xb0));
        g4 = __builtin_nontemporal_load((const f32x4*)(xb0 + HWPIX));
        b4 = __builtin_nontemporal_load((const f32x4*)(xb0 + 2 * HWPIX));
        const float* xb1 = x + p0 + (1 << 20);        // d(1) = 2^20
        nr = __builtin_nontemporal_load((const f32x4*)(xb1));
        ng = __builtin_nontemporal_load((const f32x4*)(xb1 + HWPIX));
        nb = __builtin_nontemporal_load((const f32x4*)(xb1 + 2 * HWPIX));
    }

    float s511, bias;
    lut_prologue(LUT, tab, red, tid, s511, bias);

    for (int i = 0; i < 16; ++i) {
        // ---- prefetch iter i+2 (unconditional; clamp keeps it in-bounds) ----
        int ip = min(i + 2, 15);
        int dp = ((ip >> 2) * IMG3) + ((ip & 3) << 20);
        const float* xbp = x + dp + p0;
        f32x4 pr = __builtin_nontemporal_load((const f32x4*)(xbp));
        f32x4 pg = __builtin_nontemporal_load((const f32x4*)(xbp + HWPIX));
        f32x4 pb = __builtin_nontemporal_load((const f32x4*)(xbp + 2 * HWPIX));

        f32x4 oc0, oc1, oc2;
        apply_quad(tab, r4, g4, b4, s511, bias, oc0, oc1, oc2);

        int d = ((i >> 2) * IMG3) + ((i & 3) << 20);
        float* ob = out + d + p0;
        *(f32x4*)(ob)             = oc0;
        *(f32x4*)(ob + HWPIX)     = oc1;
        *(f32x4*)(ob + 2 * HWPIX) = oc2;

        r4 = nr; g4 = ng; b4 = nb;
        nr = pr; ng = pg; nb = pb;
    }
}

// ---------------------------------------------------------------------------
// Generic path (any npix multiple of 4*HWPIX-layout): round-1 kernel.
// ---------------------------------------------------------------------------
__global__ __launch_bounds__(1024, 4) void k_lut_generic(const float* __restrict__ x,
                                                         const float* __restrict__ LUT,
                                                         float* __restrict__ out,
                                                         int nquads) {
    __shared__ u32   tab[D3];
    __shared__ float red[16];

    const int tid    = threadIdx.x;
    const int stride = (int)gridDim.x * 1024;
    int t = blockIdx.x * 1024 + tid;

    f32x4 r4 = {0.f, 0.f, 0.f, 0.f}, g4 = r4, b4 = r4;
    f32x4 nr = r4, ng = r4, nb = r4;
    if (t < nquads) {
        int p = t << 2;
        int b = p >> HWSHIFT;
        int o = p & (HWPIX - 1);
        const float* xb = x + (size_t)b * IMG3 + o;
        r4 = __builtin_nontemporal_load((const f32x4*)(xb));
        g4 = __builtin_nontemporal_load((const f32x4*)(xb + HWPIX));
        b4 = __builtin_nontemporal_load((const f32x4*)(xb + 2 * HWPIX));
    }
    {
        int t1 = t + stride;
        if (t1 < nquads) {
            int p = t1 << 2;
            int b = p >> HWSHIFT;
            int o = p & (HWPIX - 1);
            const float* xb = x + (size_t)b * IMG3 + o;
            nr = __builtin_nontemporal_load((const f32x4*)(xb));
            ng = __builtin_nontemporal_load((const f32x4*)(xb + HWPIX));
            nb = __builtin_nontemporal_load((const f32x4*)(xb + 2 * HWPIX));
        }
    }

    float s511, bias;
    lut_prologue(LUT, tab, red, tid, s511, bias);

    while (t < nquads) {
        int tn = t + stride;
        int tp = tn + stride;
        f32x4 pr = {0.f, 0.f, 0.f, 0.f}, pg = pr, pb = pr;
        if (tp < nquads) {
            int pp = tp << 2;
            int bp = pp >> HWSHIFT;
            int op = pp & (HWPIX - 1);
            const float* xbp = x + (size_t)bp * IMG3 + op;
            pr = __builtin_nontemporal_load((const f32x4*)(xbp));
            pg = __builtin_nontemporal_load((const f32x4*)(xbp + HWPIX));
            pb = __builtin_nontemporal_load((const f32x4*)(xbp + 2 * HWPIX));
        }

        f32x4 oc0, oc1, oc2;
        apply_quad(tab, r4, g4, b4, s511, bias, oc0, oc1, oc2);

        {
            int p = t << 2;
            int b = p >> HWSHIFT;
            int o = p & (HWPIX - 1);
            float* ob = out + (size_t)b * IMG3 + o;
            *(f32x4*)(ob)             = oc0;
            *(f32x4*)(ob + HWPIX)     = oc1;
            *(f32x4*)(ob + 2 * HWPIX) = oc2;
        }

        t  = tn;
        r4 = nr; g4 = ng; b4 = nb;
        nr = pr; ng = pg; nb = pb;
    }
}

extern "C" void kernel_launch(void* const* d_in, const int* in_sizes, int n_in,
                              void* d_out, int out_size, void* d_ws, size_t ws_size,
                              hipStream_t stream) {
    const float* x   = (const float*)d_in[0];
    const float* LUT = (const float*)d_in[1];
    float* out = (float*)d_out;

    int npix   = in_sizes[0] / 3;   // B*H*W
    int nquads = npix >> 2;

    if (npix == 4 * HWPIX) {
        // exact-shape fast path: 256 blocks x 1024 threads, 16 iters/thread
        k_lut_fast<<<256, 1024, 0, stream>>>(x, LUT, out);
    } else {
        k_lut_generic<<<256, 1024, 0, stream>>>(x, LUT, out, nquads);
    }
}

// Round 4
// 348.865 us; speedup vs baseline: 1.1589x; 1.1589x over previous
//
#include <hip/hip_runtime.h>

#define DIMK 33
#define D2   (DIMK * DIMK)        // 1089
#define D3   (DIMK * DIMK * DIMK) // 35937 vertices
#define HWPIX (2048 * 2048)       // 4194304 = 2^22
#define HWSHIFT 22
#define IMG3  (3 * HWPIX)

typedef float        f32x4 __attribute__((ext_vector_type(4)));
typedef unsigned int u32;

// ---------------------------------------------------------------------------
// Single fused persistent kernel, 2-deep software pipeline (round-2 structure).
//
// Grid = 256 blocks x 1024 threads; 143.8 KB static LDS -> exactly 1 block/CU
// (16 waves/CU = 4 waves/EU). __launch_bounds__(1024, 2): LDS already limits
// residency to 1 block/CU, so a 2-waves/EU floor costs nothing — it raises
// the VGPR cap to 256 so the 2-deep pipeline (9 live f32x4) + cw[4][8] never
// spills. Round 3 showed what spill/pipeline-collapse looks like: VGPR=64,
// WRITE_SIZE 2x output (scratch), all pipes <45% busy, 158 us.
//
// The while-loop with runtime bounds is deliberate: it prevents full unroll
// (round 3's unrolled exact-trip-count version collapsed the pipeline).
//
// Per pixel: 8 random ds_read_b32 (paired into ds_read2_b32) + decode.
// Since sum(w)=1: out_c = s511 * sum(w*q_c) - 512*s511.
// Stores are plain (nt stores showed 2.5x write inflation previously).
// ---------------------------------------------------------------------------
__global__ __launch_bounds__(1024, 2) void k_lut(const float* __restrict__ x,
                                                 const float* __restrict__ LUT,
                                                 float* __restrict__ out,
                                                 int nquads) {
    __shared__ u32   tab[D3];
    __shared__ float red[16];

    const int tid    = threadIdx.x;
    const int stride = (int)gridDim.x * 1024;
    int t = blockIdx.x * 1024 + tid;

    // ---- issue iteration-0 AND iteration-1 pixel loads before prologue ----
    f32x4 r4 = {0.f, 0.f, 0.f, 0.f}, g4 = r4, b4 = r4;   // iter i   (compute)
    f32x4 nr = r4, ng = r4, nb = r4;                     // iter i+1 (in flight)
    if (t < nquads) {
        int p = t << 2;
        int b = p >> HWSHIFT;
        int o = p & (HWPIX - 1);
        const float* xb = x + (size_t)b * IMG3 + o;
        r4 = __builtin_nontemporal_load((const f32x4*)(xb));
        g4 = __builtin_nontemporal_load((const f32x4*)(xb + HWPIX));
        b4 = __builtin_nontemporal_load((const f32x4*)(xb + 2 * HWPIX));
    }
    {
        int t1 = t + stride;
        if (t1 < nquads) {
            int p = t1 << 2;
            int b = p >> HWSHIFT;
            int o = p & (HWPIX - 1);
            const float* xb = x + (size_t)b * IMG3 + o;
            nr = __builtin_nontemporal_load((const f32x4*)(xb));
            ng = __builtin_nontemporal_load((const f32x4*)(xb + HWPIX));
            nb = __builtin_nontemporal_load((const f32x4*)(xb + 2 * HWPIX));
        }
    }

    // ---- pass 1: block-private absmax over all 3*D3 floats ----
    // fmax over floats is exact -> identical result in every block.
    float m = 0.0f;
    {
        const int n4 = (3 * D3) >> 2;             // 26952 f32x4 groups
        const f32x4* L4 = (const f32x4*)LUT;
        for (int i = tid; i < n4; i += 1024) {
            f32x4 v = L4[i];
            m = fmaxf(m, fmaxf(fmaxf(fabsf(v.x), fabsf(v.y)),
                               fmaxf(fabsf(v.z), fabsf(v.w))));
        }
        for (int i = (n4 << 2) + tid; i < 3 * D3; i += 1024)  // 3-elem tail
            m = fmaxf(m, fabsf(LUT[i]));
    }
    for (int off = 32; off; off >>= 1)
        m = fmaxf(m, __shfl_down(m, off, 64));
    if ((tid & 63) == 0) red[tid >> 6] = m;
    __syncthreads();
    if (tid == 0) {
        float mm = red[0];
#pragma unroll
        for (int i = 1; i < 16; ++i) mm = fmaxf(mm, red[i]);
        red[0] = fmaxf(mm, 1e-20f);
    }
    __syncthreads();
    const float s    = red[0];
    const float inv  = 511.0f / s;
    const float s511 = s * (1.0f / 511.0f);
    const float bias = 512.0f * s511;

    // ---- pass 2: quantize the whole LUT straight into LDS ----
    // word = (q0+512) | (q1+512)<<10 | (q2+512)<<20, q = round(v/s * 511)
    for (int v = tid; v < D3; v += 1024) {
        u32 w = 0;
#pragma unroll
        for (int c = 0; c < 3; ++c) {
            float vv = LUT[c * D3 + v];
            int q = (int)rintf(vv * inv);
            q = max(-511, min(511, q));
            w |= ((u32)(q + 512)) << (10 * c);
        }
        tab[v] = w;
    }
    __syncthreads();

    // ---- 2-deep pipelined apply loop ----
    while (t < nquads) {
        int tn = t + stride;          // its loads are already in flight (nr..)
        int tp = tn + stride;         // prefetch target: iter i+2
        f32x4 pr = {0.f, 0.f, 0.f, 0.f}, pg = pr, pb = pr;
        if (tp < nquads) {
            int pp = tp << 2;
            int bp = pp >> HWSHIFT;
            int op = pp & (HWPIX - 1);
            const float* xbp = x + (size_t)bp * IMG3 + op;
            pr = __builtin_nontemporal_load((const f32x4*)(xbp));
            pg = __builtin_nontemporal_load((const f32x4*)(xbp + HWPIX));
            pb = __builtin_nontemporal_load((const f32x4*)(xbp + 2 * HWPIX));
        }

        // phase 1: indices + fractions for all 4 pixels
        int   vid[4];
        float fr[4], fg[4], fb[4];
#pragma unroll
        for (int i = 0; i < 4; ++i) {
            float cr = r4[i] * 32.0f;
            float cg = g4[i] * 32.0f;
            float cb = b4[i] * 32.0f;
            int ri = max(0, min(31, (int)cr));
            int gi = max(0, min(31, (int)cg));
            int bi = max(0, min(31, (int)cb));
            fr[i] = cr - (float)ri;
            fg[i] = cg - (float)gi;
            fb[i] = cb - (float)bi;
            vid[i] = bi * D2 + gi * DIMK + ri;
        }

        // phase 2: all 32 LDS reads (pairs -> ds_read2_b32)
        u32 cw[4][8];
#pragma unroll
        for (int i = 0; i < 4; ++i) {
            int v = vid[i];
            cw[i][0] = tab[v];
            cw[i][1] = tab[v + 1];
            cw[i][2] = tab[v + DIMK];
            cw[i][3] = tab[v + DIMK + 1];
            cw[i][4] = tab[v + D2];
            cw[i][5] = tab[v + D2 + 1];
            cw[i][6] = tab[v + D2 + DIMK];
            cw[i][7] = tab[v + D2 + DIMK + 1];
        }

        // phase 3: decode + interpolate
        f32x4 oc0, oc1, oc2;
#pragma unroll
        for (int i = 0; i < 4; ++i) {
            float wr0 = 1.0f - fr[i], wg0 = 1.0f - fg[i], wb0 = 1.0f - fb[i];
            float wbg00 = wb0 * wg0,   wbg01 = wb0 * fg[i];
            float wbg10 = fb[i] * wg0, wbg11 = fb[i] * fg[i];
            float w[8] = {wbg00 * wr0, wbg00 * fr[i], wbg01 * wr0, wbg01 * fr[i],
                          wbg10 * wr0, wbg10 * fr[i], wbg11 * wr0, wbg11 * fr[i]};
            float A0 = 0.f, A1 = 0.f, A2 = 0.f;
#pragma unroll
            for (int cn = 0; cn < 8; ++cn) {
                u32 c = cw[i][cn];
                A0 += w[cn] * (float)(c & 1023u);
                A1 += w[cn] * (float)((c >> 10) & 1023u);
                A2 += w[cn] * (float)((c >> 20) & 1023u);
            }
            oc0[i] = A0 * s511 - bias;
            oc1[i] = A1 * s511 - bias;
            oc2[i] = A2 * s511 - bias;
        }

        // store (plain, not nt)
        {
            int p = t << 2;
            int b = p >> HWSHIFT;
            int o = p & (HWPIX - 1);
            float* ob = out + (size_t)b * IMG3 + o;
            *(f32x4*)(ob)             = oc0;
            *(f32x4*)(ob + HWPIX)     = oc1;
            *(f32x4*)(ob + 2 * HWPIX) = oc2;
        }

        // rotate pipeline registers
        t  = tn;
        r4 = nr; g4 = ng; b4 = nb;
        nr = pr; ng = pg; nb = pb;
    }
}

extern "C" void kernel_launch(void* const* d_in, const int* in_sizes, int n_in,
                              void* d_out, int out_size, void* d_ws, size_t ws_size,
                              hipStream_t stream) {
    const float* x   = (const float*)d_in[0];
    const float* LUT = (const float*)d_in[1];
    float* out = (float*)d_out;

    int npix   = in_sizes[0] / 3;   // B*H*W = 16,777,216
    int nquads = npix >> 2;         // 4,194,304 quads

    // 256 blocks = exactly 1 resident block per CU (LDS-limited), persistent
    // grid-stride: 16 quads/thread, LDS staged once per CU.
    k_lut<<<256, 1024, 0, stream>>>(x, LUT, out, nquads);
}